// Round 5
// baseline (584.415 us; speedup 1.0000x reference)
//
#include <hip/hip_runtime.h>

// Gaussian blur 21x21, sigma=5, depthwise over [B=32, C=3, H=512, W=512] fp32,
// reflect padding, separable, fused single kernel.
//
// R5: vertical-first restructure. All memory patterns provably clean:
//  - Phase 1 (vertical, global->LDS): lane = x, so every global load is a
//    contiguous 64-float row segment (perfect coalescing; y-halo 1.24x, L2).
//    Each thread register-blocks 32 output rows (52 sliding loads).
//    Result written TRANSPOSED: s_v[x][y], stride 65 -> banks (x+y)%32,
//    2 lanes/bank = free (m136).
//  - Phase 2 (horizontal from s_v): wave-uniform col + lane=y b32 reads
//    (2 lanes/bank, free); 16 cols/wave register block: 36 reads -> 16x64 out.
//    Written to s_t[y][c], stride 65 -> banks (y+c)%32, free.
//  - Phase 3: s_t row-major read + contiguous global store (both free/coalesced).
// LDS 21840 + 16640 = 38480 B -> 4 blocks/CU (153.9 KB), 16 waves/CU.

#define KS   21
#define PAD  10
#define TILE 64
#define IMG  512
#define NT   256
#define SV   65   // s_v stride: s_v[x][y] at x*SV+y, x in [0,84), y in [0,64)
#define ST   65   // s_t stride: s_t[y][c] at y*ST+c

__global__ __launch_bounds__(NT) void gauss_blur_kernel(
    const float* __restrict__ in, float* __restrict__ out)
{
    __shared__ float s_v[84 * SV];   // 21840 B, v-blurred, transposed
    __shared__ float s_t[64 * ST];   // 16640 B, final tile, row-major

    // exp(-(k-10)^2/50), normalized (sum(outer(g,g)) = sum(g)^2, so 1-D
    // normalization reproduces the reference's 2-D normalization).
    constexpr float W[KS] = {
        0.011194717f, 0.016369860f, 0.022998804f, 0.031045124f, 0.040263373f,
        0.050171245f, 0.060066033f, 0.069092259f, 0.076358728f, 0.081080459f,
        0.082718387f,
        0.081080459f, 0.076358728f, 0.069092259f, 0.060066033f, 0.050171245f,
        0.040263373f, 0.031045124f, 0.022998804f, 0.016369860f, 0.011194717f
    };

    const int tid   = threadIdx.x;
    const int wv    = tid >> 6;       // wave 0..3
    const int ln    = tid & 63;       // lane
    const int plane = blockIdx.z;     // b*C + c, 0..95
    const int x0    = blockIdx.x * TILE;
    const int y0    = blockIdx.y * TILE;

    const float* __restrict__ pin = in + (size_t)plane * (IMG * IMG);

    // ---- phase 1: vertical 21-tap from GLOBAL -> s_v (transposed) ----
    // items: 84 cols x 2 strips(32 rows). W0: cols 0-63 strip 0; W1: strip 1;
    // W2: cols 64-83 strip 0 (lanes 0-19); W3: cols 64-83 strip 1.
    {
        int col, s;
        bool active;
        if (wv < 2) { col = ln;      s = wv;     active = true; }
        else        { col = 64 + ln; s = wv - 2; active = (ln < 20); }

        if (active) {
            int gx = x0 - PAD + col;                 // fixed per thread; reflect once
            gx = (gx < 0) ? -gx : gx;
            gx = (gx >= IMG) ? (2 * IMG - 2 - gx) : gx;

            float acc[32];
#pragma unroll
            for (int j = 0; j < 32; ++j) acc[j] = 0.f;

            const int ybase = y0 + 32 * s - PAD;     // first input row of strip

            if (y0 >= PAD && y0 + 73 < IMG) {
                // y-interior block: monotone rows, no reflect
                const float* __restrict__ p = pin + (size_t)ybase * IMG + gx;
#pragma unroll
                for (int t = 0; t < 52; ++t) {
                    float r = p[(size_t)t * IMG];
#pragma unroll
                    for (int j = 0; j < 32; ++j)
                        if (j >= t - (KS - 1) && j <= t) acc[j] += W[t - j] * r;
                }
            } else {
#pragma unroll
                for (int t = 0; t < 52; ++t) {
                    int gy = ybase + t;
                    gy = (gy < 0) ? -gy : gy;
                    gy = (gy >= IMG) ? (2 * IMG - 2 - gy) : gy;
                    float r = pin[(size_t)gy * IMG + gx];
#pragma unroll
                    for (int j = 0; j < 32; ++j)
                        if (j >= t - (KS - 1) && j <= t) acc[j] += W[t - j] * r;
                }
            }
            // transposed write: lanes differ in col -> banks (col + const)%32, free
#pragma unroll
            for (int j = 0; j < 32; ++j) s_v[col * SV + 32 * s + j] = acc[j];
        }
    }
    __syncthreads();

    // ---- phase 2: horizontal 21-tap from s_v -> s_t ----
    // wave w: output cols c0..c0+15 (c0 = 16w), all 64 rows (lane = y).
    // out col c = sum_k W[k] * s_v[c + k][y]  (s_v col 0 == global x0-10)
    {
        const int c0 = wv << 4;
        float acc[16];
#pragma unroll
        for (int u = 0; u < 16; ++u) acc[u] = 0.f;

#pragma unroll
        for (int t = 0; t < 36; ++t) {   // s_v cols c0..c0+35
            float r = s_v[(c0 + t) * SV + ln];   // lane-contiguous b32, free
#pragma unroll
            for (int u = 0; u < 16; ++u)
                if (u >= t - (KS - 1) && u <= t) acc[u] += W[t - u] * r;
        }
        // s_t[y][c0+u]: lanes differ in y -> banks (y + const)%32, free
#pragma unroll
        for (int u = 0; u < 16; ++u) s_t[ln * ST + c0 + u] = acc[u];
    }
    __syncthreads();

    // ---- phase 3: coalesced store ----
    {
        float* __restrict__ pout = out + (size_t)plane * (IMG * IMG)
                                       + (size_t)y0 * IMG + x0;
#pragma unroll
        for (int i = 0; i < 16; ++i) {
            int r = (wv << 4) + i;
            pout[(size_t)r * IMG + ln] = s_t[r * ST + ln];  // 256B contiguous
        }
    }
}

extern "C" void kernel_launch(void* const* d_in, const int* in_sizes, int n_in,
                              void* d_out, int out_size, void* d_ws, size_t ws_size,
                              hipStream_t stream)
{
    const float* x = (const float*)d_in[0];
    float* out = (float*)d_out;

    dim3 grid(IMG / TILE, IMG / TILE, 96);   // 8 x 8 x (32*3) planes
    dim3 block(NT);
    gauss_blur_kernel<<<grid, block, 0, stream>>>(x, out);
}

// Round 6
// 515.262 us; speedup vs baseline: 1.1342x; 1.1342x over previous
//
#include <hip/hip_runtime.h>

// Gaussian blur 21x21, sigma=5, depthwise over [B=32, C=3, H=512, W=512] fp32,
// reflect padding, separable, fused single kernel.
//
// R6: only proven-good access patterns (R3 staging + R5 LDS discipline).
//  Phase A: global->s_raw[84][88] staging. Interior-x: lane-contiguous float4
//           global loads -> LINEAR contiguous b128 LDS writes (R3-proven).
//  Phase B: vertical 21-tap from s_raw: wave = 32-row strip x 64/24-col chunk,
//           reads wave-uniform row + lane-contiguous b32 (2/bank = free),
//           write s_v[y][col] stride 89 (uniform row, lanes contiguous, free).
//  Phase C: horizontal 21-tap from s_v: wave-uniform col + lane=y, stride 89
//           (odd -> bank permutation, free); 16 cols/wave, 36 reads/wave.
//           write s_t[y][c] stride 65 (lane-stride odd, free).
//  Phase D: s_t row-major read (uniform row, contiguous) -> 256B coalesced store.
//  s_t aliases dead s_raw. LDS 29568+22784 = 52.3 KB -> 3 blocks/CU.

#define KS   21
#define PAD  10
#define TILE 64
#define IMG  512
#define NT   256
#define RAW_W 88        // s_raw cols: gx = x0-12+col, col 0..87
#define RAW_H 84        // s_raw rows: gy = y0-10+row
#define SV    89        // s_v stride (odd; 89%32=25, gcd(25,32)=1)
#define STT   65        // s_t stride (odd)

__global__ __launch_bounds__(NT) void gauss_blur_kernel(
    const float* __restrict__ in, float* __restrict__ out)
{
    __shared__ __align__(16) unsigned char s_mem[RAW_H * RAW_W * 4 + 64 * SV * 4];
    float* const s_raw = (float*)s_mem;                      // [84][88]
    float* const s_v   = (float*)(s_mem + RAW_H * RAW_W * 4); // [64][89] (y, col)
    float* const s_t   = (float*)s_mem;                      // [64][65] aliases s_raw

    // exp(-(k-10)^2/50), normalized (sum(outer(g,g)) = sum(g)^2, so 1-D
    // normalization reproduces the reference's 2-D normalization).
    constexpr float W[KS] = {
        0.011194717f, 0.016369860f, 0.022998804f, 0.031045124f, 0.040263373f,
        0.050171245f, 0.060066033f, 0.069092259f, 0.076358728f, 0.081080459f,
        0.082718387f,
        0.081080459f, 0.076358728f, 0.069092259f, 0.060066033f, 0.050171245f,
        0.040263373f, 0.031045124f, 0.022998804f, 0.016369860f, 0.011194717f
    };

    const int tid   = threadIdx.x;
    const int wv    = tid >> 6;
    const int ln    = tid & 63;
    const int plane = blockIdx.z;                 // b*C + c, 0..95
    const int x0    = blockIdx.x * TILE;
    const int y0    = blockIdx.y * TILE;

    const float* __restrict__ pin = in + (size_t)plane * (IMG * IMG);

    // ---- phase A: global -> s_raw (rows y0-10.., cols x0-12..x0+75) ----
    const bool x_int = (blockIdx.x != 0) && (blockIdx.x != (IMG / TILE - 1));
    if (x_int) {
        // 84 rows x 22 float4 = 1848 vec loads; LDS writes are LINEAR contiguous
        for (int q = tid; q < RAW_H * (RAW_W / 4); q += NT) {
            int ly  = q / (RAW_W / 4);
            int lx4 = q - ly * (RAW_W / 4);
            int gy  = y0 + ly - PAD;
            gy = (gy < 0) ? -gy : ((gy >= IMG) ? (2 * IMG - 2 - gy) : gy);
            // (x0-12)*4 % 16 == 0 -> aligned float4
            float4 f = *(const float4*)&pin[(size_t)gy * IMG + (x0 - 12) + 4 * lx4];
            *(float4*)&s_raw[q * 4] = f;
        }
    } else {
        // x-border blocks (2 of 8): scalar reflect path
        for (int q = tid; q < RAW_H * RAW_W; q += NT) {
            int ly = q / RAW_W;
            int lx = q - ly * RAW_W;
            int gy = y0 + ly - PAD;
            int gx = x0 + lx - 12;
            gy = (gy < 0) ? -gy : ((gy >= IMG) ? (2 * IMG - 2 - gy) : gy);
            gx = (gx < 0) ? -gx : ((gx >= IMG) ? (2 * IMG - 2 - gx) : gx);
            s_raw[q] = pin[(size_t)gy * IMG + gx];
        }
    }
    __syncthreads();

    // ---- phase B: vertical 21-tap, s_raw -> s_v (all 88 cols, 64 out rows) ----
    // wave: 32-row strip x col chunk. wv0: rows 0-31 cols 0-63; wv1: rows 32-63
    // cols 0-63; wv2/3: same strips, cols 64-87 (24 lanes active).
    {
        const int rs  = (wv & 1) * 32;
        const int col = (wv >> 1) * 64 + ln;
        if (col < RAW_W) {
            float acc[32];
#pragma unroll
            for (int j = 0; j < 32; ++j) acc[j] = 0.f;
#pragma unroll
            for (int t = 0; t < 52; ++t) {
                float r = s_raw[(rs + t) * RAW_W + col];  // uniform row, lanes contig
#pragma unroll
                for (int j = 0; j < 32; ++j)
                    if (j >= t - (KS - 1) && j <= t) acc[j] += W[t - j] * r;
            }
#pragma unroll
            for (int j = 0; j < 32; ++j)
                s_v[(rs + j) * SV + col] = acc[j];        // uniform row, lanes contig
        }
    }
    __syncthreads();

    // ---- phase C: horizontal 21-tap, s_v -> s_t ----
    // out col c = sum_k W[k] * v[y][c+2+k]; wave handles cols c0..c0+15, lane=y.
    {
        const int c0 = wv << 4;
        float acc[16];
#pragma unroll
        for (int u = 0; u < 16; ++u) acc[u] = 0.f;
#pragma unroll
        for (int t = 0; t < 36; ++t) {
            float r = s_v[ln * SV + (2 + c0 + t)];        // lane-stride 89: odd, free
#pragma unroll
            for (int u = 0; u < 16; ++u)
                if (u >= t - (KS - 1) && u <= t) acc[u] += W[t - u] * r;
        }
#pragma unroll
        for (int u = 0; u < 16; ++u)
            s_t[ln * STT + c0 + u] = acc[u];              // lane-stride 65: odd, free
    }
    __syncthreads();

    // ---- phase D: transpose-back store, 256B contiguous per wave-row ----
    {
        float* __restrict__ pout = out + (size_t)plane * (IMG * IMG)
                                       + (size_t)y0 * IMG + x0;
#pragma unroll
        for (int i = 0; i < 16; ++i) {
            int r = (wv << 4) + i;
            pout[(size_t)r * IMG + ln] = s_t[r * STT + ln]; // uniform row, contig
        }
    }
}

extern "C" void kernel_launch(void* const* d_in, const int* in_sizes, int n_in,
                              void* d_out, int out_size, void* d_ws, size_t ws_size,
                              hipStream_t stream)
{
    const float* x = (const float*)d_in[0];
    float* out = (float*)d_out;

    dim3 grid(IMG / TILE, IMG / TILE, 96);   // 8 x 8 x (32*3) planes
    dim3 block(NT);
    gauss_blur_kernel<<<grid, block, 0, stream>>>(x, out);
}